// Round 1
// baseline (476.452 us; speedup 1.0000x reference)
//
#include <hip/hip_runtime.h>

typedef float f32x4 __attribute__((ext_vector_type(4)));
typedef short s16x8 __attribute__((ext_vector_type(8)));

#define MFMA16 __builtin_amdgcn_mfma_f32_16x16x32_bf16

__device__ __forceinline__ unsigned short f2bf(float f) {
    union { float f; unsigned u; } v; v.f = f;
    unsigned r = v.u + 0x7FFF + ((v.u >> 16) & 1);   // RNE
    return (unsigned short)(r >> 16);
}

// ---------------------------------------------------------------------------
// Kernel 0: convert W [1024][64] fp32 -> W_t [192][1024] bf16 (transposed).
// cols 0..63 = Wq (prescaled by 0.125 = H^-0.5), 64..127 = Wk, 128..191 = Wv
// ---------------------------------------------------------------------------
__global__ void prep_w(const float* __restrict__ Wk, const float* __restrict__ Wq,
                       const float* __restrict__ Wv, unsigned short* __restrict__ wt) {
    int n = blockIdx.x;          // 0..191
    int tid = threadIdx.x;       // 0..255
    const float* src; int col; float sc = 1.0f;
    if (n < 64)       { src = Wq; col = n;       sc = 0.125f; }
    else if (n < 128) { src = Wk; col = n - 64; }
    else              { src = Wv; col = n - 128; }
#pragma unroll
    for (int i = 0; i < 4; i++) {
        int c = i * 256 + tid;
        wt[n * 1024 + c] = f2bf(src[c * 64 + col] * sc);
    }
}

// ---------------------------------------------------------------------------
// Fused kernel: one block per batch (grid=256, 512 threads = 8 waves).
// Phase 1: qkv projection, wave w computes rows [32w,32w+32) x 192 cols,
//          A-frags direct from global x (fp32->bf16, dist-1 prefetch),
//          B-frags direct from L2-resident wt. No barriers in K-loop.
//          Epilogue: Q,K row-major + V transposed -> LDS. One barrier.
// Phase 2: causal flash attention from LDS. Wave w handles Q-tiles
//          {w, 15-w} (16 rows each) for balanced causal work.
// ---------------------------------------------------------------------------
__global__ __launch_bounds__(512, 2) void fused_kernel(const float* __restrict__ x,
                                                       const unsigned short* __restrict__ wt,
                                                       float* __restrict__ out) {
    __shared__ unsigned short Ql[256 * 72];   // row stride 72 (144B, 16B-mult)
    __shared__ unsigned short Kl[256 * 72];
    __shared__ unsigned short Vt[64 * 264];   // V^T [h][s], row stride 264
    __shared__ unsigned short Pl[8][16 * 56]; // per-wave P scratch

    const int tid  = threadIdx.x;
    const int lane = tid & 63;
    const int wid  = tid >> 6;       // 0..7
    const int quad = lane >> 4;
    const int l15  = lane & 15;
    const int b    = blockIdx.x;
    const int m0   = wid * 32;

    const float* xb = x + (long)b * 256 * 1024;

    // ======== phase 1: QKV projection ========
    f32x4 acc[2][12] = {};

    const float* arow0 = xb + (long)(m0 + l15) * 1024 + quad * 8;
    const float* arow1 = arow0 + 16 * 1024;
    const unsigned short* wrow = wt + (long)l15 * 1024 + quad * 8;

    float4 pa0 = *(const float4*)(arow0);
    float4 pa1 = *(const float4*)(arow0 + 4);
    float4 pa2 = *(const float4*)(arow1);
    float4 pa3 = *(const float4*)(arow1 + 4);

    for (int k0 = 0; k0 < 1024; k0 += 32) {
        // B frags for this step (L2-resident wt)
        s16x8 bf[12];
#pragma unroll
        for (int nt = 0; nt < 12; nt++)
            bf[nt] = *(const s16x8*)(wrow + (long)nt * 16 * 1024 + k0);

        // convert current A (loaded last iteration)
        s16x8 af0 = { (short)f2bf(pa0.x), (short)f2bf(pa0.y), (short)f2bf(pa0.z), (short)f2bf(pa0.w),
                      (short)f2bf(pa1.x), (short)f2bf(pa1.y), (short)f2bf(pa1.z), (short)f2bf(pa1.w) };
        s16x8 af1 = { (short)f2bf(pa2.x), (short)f2bf(pa2.y), (short)f2bf(pa2.z), (short)f2bf(pa2.w),
                      (short)f2bf(pa3.x), (short)f2bf(pa3.y), (short)f2bf(pa3.z), (short)f2bf(pa3.w) };

        // prefetch next step's A (HBM) — keeps ~4KB/wave in flight
        const int kn = (k0 + 32 < 1024) ? k0 + 32 : 0;
        pa0 = *(const float4*)(arow0 + kn);
        pa1 = *(const float4*)(arow0 + kn + 4);
        pa2 = *(const float4*)(arow1 + kn);
        pa3 = *(const float4*)(arow1 + kn + 4);

#pragma unroll
        for (int nt = 0; nt < 12; nt++) {
            acc[0][nt] = MFMA16(af0, bf[nt], acc[0][nt], 0, 0, 0);
            acc[1][nt] = MFMA16(af1, bf[nt], acc[1][nt], 0, 0, 0);
        }
    }

    // ---- epilogue: Q,K row-major; V transposed (acc regs hold 4 consecutive rows) ----
#pragma unroll
    for (int mt = 0; mt < 2; mt++) {
#pragma unroll
        for (int nt = 0; nt < 12; nt++) {
            if (nt < 4) {
#pragma unroll
                for (int r = 0; r < 4; r++)
                    Ql[(m0 + mt * 16 + quad * 4 + r) * 72 + nt * 16 + l15] = f2bf(acc[mt][nt][r]);
            } else if (nt < 8) {
#pragma unroll
                for (int r = 0; r < 4; r++)
                    Kl[(m0 + mt * 16 + quad * 4 + r) * 72 + (nt - 4) * 16 + l15] = f2bf(acc[mt][nt][r]);
            } else {
                ushort4 pv;
                pv.x = f2bf(acc[mt][nt][0]); pv.y = f2bf(acc[mt][nt][1]);
                pv.z = f2bf(acc[mt][nt][2]); pv.w = f2bf(acc[mt][nt][3]);
                *(ushort4*)&Vt[((nt - 8) * 16 + l15) * 264 + m0 + mt * 16 + quad * 4] = pv;
            }
        }
    }
    __syncthreads();

    // ======== phase 2: causal attention ========
    unsigned short* Pw = &Pl[wid][0];

#pragma unroll
    for (int ti = 0; ti < 2; ti++) {
        const int r0 = (ti == 0 ? wid : 15 - wid) * 16;   // balanced tile pair

        s16x8 qf0 = *(const s16x8*)&Ql[(r0 + l15) * 72 + quad * 8];
        s16x8 qf1 = *(const s16x8*)&Ql[(r0 + l15) * 72 + 32 + quad * 8];

        f32x4 o[4] = {};
        float mr[4], lr[4];
#pragma unroll
        for (int r = 0; r < 4; r++) { mr[r] = -1e30f; lr[r] = 0.0f; }

        const int nst = (r0 >> 5) + 1;
        for (int st = 0; st < nst; st++) {
            const int s0 = st * 32;
            s16x8 kf00 = *(const s16x8*)&Kl[(s0 + l15) * 72 + quad * 8];
            s16x8 kf01 = *(const s16x8*)&Kl[(s0 + l15) * 72 + 32 + quad * 8];
            s16x8 kf10 = *(const s16x8*)&Kl[(s0 + 16 + l15) * 72 + quad * 8];
            s16x8 kf11 = *(const s16x8*)&Kl[(s0 + 16 + l15) * 72 + 32 + quad * 8];
            s16x8 vf[4];
#pragma unroll
            for (int n = 0; n < 4; n++)
                vf[n] = *(const s16x8*)&Vt[(n * 16 + l15) * 264 + s0 + quad * 8];

            f32x4 S0 = {0.f, 0.f, 0.f, 0.f}, S1 = {0.f, 0.f, 0.f, 0.f};
            S0 = MFMA16(qf0, kf00, S0, 0, 0, 0);
            S0 = MFMA16(qf1, kf01, S0, 0, 0, 0);
            S1 = MFMA16(qf0, kf10, S1, 0, 0, 0);
            S1 = MFMA16(qf1, kf11, S1, 0, 0, 0);

            if (s0 + 31 > r0) {   // diagonal tile: causal mask
#pragma unroll
                for (int r = 0; r < 4; r++) {
                    int t = r0 + quad * 4 + r;
                    if (s0 + l15 > t)      S0[r] = -1e30f;
                    if (s0 + 16 + l15 > t) S1[r] = -1e30f;
                }
            }

            float a4[4];
#pragma unroll
            for (int r = 0; r < 4; r++) {
                float rm = fmaxf(S0[r], S1[r]);
                rm = fmaxf(rm, __shfl_xor(rm, 1));
                rm = fmaxf(rm, __shfl_xor(rm, 2));
                rm = fmaxf(rm, __shfl_xor(rm, 4));
                rm = fmaxf(rm, __shfl_xor(rm, 8));
                float mn = fmaxf(mr[r], rm);
                float al = exp2f((mr[r] - mn) * 1.44269504f);
                mr[r] = mn;
                float p0 = exp2f((S0[r] - mn) * 1.44269504f);
                float p1 = exp2f((S1[r] - mn) * 1.44269504f);
                float rs = p0 + p1;
                rs += __shfl_xor(rs, 1);
                rs += __shfl_xor(rs, 2);
                rs += __shfl_xor(rs, 4);
                rs += __shfl_xor(rs, 8);
                lr[r] = al * lr[r] + rs;
                a4[r] = al;
                Pw[(quad * 4 + r) * 56 + l15]      = f2bf(p0);
                Pw[(quad * 4 + r) * 56 + l15 + 16] = f2bf(p1);
            }
#pragma unroll
            for (int n = 0; n < 4; n++) {
                f32x4 t = o[n];
#pragma unroll
                for (int r = 0; r < 4; r++) t[r] *= a4[r];
                o[n] = t;
            }
            s16x8 pf = *(const s16x8*)&Pw[l15 * 56 + quad * 8];
#pragma unroll
            for (int n = 0; n < 4; n++)
                o[n] = MFMA16(pf, vf[n], o[n], 0, 0, 0);
        }

        // ---- normalize + store ----
        float inv[4];
#pragma unroll
        for (int r = 0; r < 4; r++) inv[r] = 1.0f / lr[r];
#pragma unroll
        for (int n = 0; n < 4; n++)
#pragma unroll
            for (int r = 0; r < 4; r++) {
                long t = (long)b * 256 + r0 + quad * 4 + r;
                out[t * 64 + n * 16 + l15] = o[n][r] * inv[r];
            }
    }
}

// ---------------------------------------------------------------------------
extern "C" void kernel_launch(void* const* d_in, const int* in_sizes, int n_in,
                              void* d_out, int out_size, void* d_ws, size_t ws_size,
                              hipStream_t stream) {
    const float* x  = (const float*)d_in[0];
    const float* Wk = (const float*)d_in[1];
    const float* Wq = (const float*)d_in[2];
    const float* Wv = (const float*)d_in[3];
    float* out = (float*)d_out;

    unsigned short* wt = (unsigned short*)d_ws;   // 192*1024 bf16

    prep_w<<<192, 256, 0, stream>>>(Wk, Wq, Wv, wt);
    fused_kernel<<<256, 512, 0, stream>>>(x, wt, out);
}

// Round 2
// 409.383 us; speedup vs baseline: 1.1638x; 1.1638x over previous
//
#include <hip/hip_runtime.h>

typedef float f32x4 __attribute__((ext_vector_type(4)));
typedef short s16x8 __attribute__((ext_vector_type(8)));

#define MFMA16 __builtin_amdgcn_mfma_f32_16x16x32_bf16

typedef const __attribute__((address_space(1))) void* gptr_t;
typedef __attribute__((address_space(3))) void* lptr_t;

__device__ __forceinline__ unsigned short f2bf(float f) {
    union { float f; unsigned u; } v; v.f = f;
    unsigned r = v.u + 0x7FFF + ((v.u >> 16) & 1);   // RNE
    return (unsigned short)(r >> 16);
}

// ---------------------------------------------------------------------------
// Kernel 0: convert W [1024][64] fp32 -> W_t [192][1024] bf16 (transposed).
// cols 0..63 = Wq (prescaled by 0.125 = H^-0.5), 64..127 = Wk, 128..191 = Wv
// ---------------------------------------------------------------------------
__global__ void prep_w(const float* __restrict__ Wk, const float* __restrict__ Wq,
                       const float* __restrict__ Wv, unsigned short* __restrict__ wt) {
    int n = blockIdx.x;          // 0..191
    int tid = threadIdx.x;       // 0..255
    const float* src; int col; float sc = 1.0f;
    if (n < 64)       { src = Wq; col = n;       sc = 0.125f; }
    else if (n < 128) { src = Wk; col = n - 64; }
    else              { src = Wv; col = n - 128; }
#pragma unroll
    for (int i = 0; i < 4; i++) {
        int c = i * 256 + tid;
        wt[n * 1024 + c] = f2bf(src[c * 64 + col] * sc);
    }
}

// ---------------------------------------------------------------------------
// Fused kernel: one block per batch (grid=256, 512 threads = 8 waves).
// Phase 1: qkv projection. Per 64-wide K-slab: wt tile [192][64] staged ONCE
//          per block into LDS via global_load_lds (linear dest, pre-swizzled
//          source; XOR-swizzled ds_read => conflict-free). x direct to regs
//          (read exactly once). Cuts wt L2/L3 traffic 8x (805MB -> 100MB).
// Phase 2: causal flash attention from LDS. Wave w handles Q-tiles
//          {w, 15-w} (16 rows each) for balanced causal work.
// ---------------------------------------------------------------------------
__global__ __launch_bounds__(512, 2) void fused_kernel(const float* __restrict__ x,
                                                       const unsigned short* __restrict__ wt,
                                                       float* __restrict__ out) {
    // carved shared block: Ql[256*72] | Kl[256*72] | Vt[64*264] | Pl[8][16*56]
    // Wl[192][64] (24KB, proj phase only) aliases the Ql region.
    __shared__ unsigned short smem[2 * 256 * 72 + 64 * 264 + 8 * 16 * 56];
    unsigned short* Ql  = smem;
    unsigned short* Kl  = smem + 256 * 72;
    unsigned short* Vt  = smem + 2 * 256 * 72;
    unsigned short* Pl8 = smem + 2 * 256 * 72 + 64 * 264;
    unsigned short* Wl  = smem;   // [192][64] bf16, swizzled chunks

    const int tid  = threadIdx.x;
    const int lane = tid & 63;
    const int wid  = tid >> 6;       // 0..7
    const int quad = lane >> 4;
    const int l15  = lane & 15;
    const int b    = blockIdx.x;
    const int m0   = wid * 32;

    const float* xb  = x + (long)b * 256 * 1024;
    const float* ar0 = xb + (long)(m0 + l15) * 1024 + quad * 8;
    const float* ar1 = ar0 + 16 * 1024;

    // wt staging: wave w stages rows [24w, 24w+24), 3 global_load_lds of 1KB.
    const int srow = wid * 24 + (lane >> 3);   // slot row for j=0
    const int cswz = (lane & 7) ^ (srow & 7);  // pre-swizzled source chunk (j-invariant)

    // ds_read swizzle: rr&7 == l15&7 for all nt
    const unsigned short* wbase0 = Wl + l15 * 64 + ((0 + quad) ^ (l15 & 7)) * 8;  // kk=0
    const unsigned short* wbase1 = Wl + l15 * 64 + ((4 + quad) ^ (l15 & 7)) * 8;  // kk=32

    // ======== phase 1: QKV projection ========
    f32x4 acc[2][12] = {};

    for (int t = 0; t < 16; t++) {
        const int k0 = t * 64;
        if (t) __syncthreads();          // all waves done reading previous slab
        // ---- stage wt slab [192][64] -> LDS (once per block) ----
#pragma unroll
        for (int j = 0; j < 3; j++) {
            const unsigned short* src = wt + (long)(srow + j * 8) * 1024 + k0 + cswz * 8;
            unsigned short* dst = Wl + (wid * 24 + j * 8) * 64;   // wave-uniform base
            __builtin_amdgcn_global_load_lds((gptr_t)src, (lptr_t)dst, 16, 0, 0);
        }
        // ---- x loads for this slab (each row read exactly once) ----
        float4 px0 = *(const float4*)(ar0 + k0);
        float4 px1 = *(const float4*)(ar0 + k0 + 4);
        float4 px2 = *(const float4*)(ar0 + k0 + 32);
        float4 px3 = *(const float4*)(ar0 + k0 + 36);
        float4 px4 = *(const float4*)(ar1 + k0);
        float4 px5 = *(const float4*)(ar1 + k0 + 4);
        float4 px6 = *(const float4*)(ar1 + k0 + 32);
        float4 px7 = *(const float4*)(ar1 + k0 + 36);
        __syncthreads();                 // compiler drains vmcnt: slab + px ready

#pragma unroll
        for (int kk = 0; kk < 64; kk += 32) {
            s16x8 bfv[12];
            const unsigned short* wb = (kk == 0) ? wbase0 : wbase1;
#pragma unroll
            for (int nt = 0; nt < 12; nt++)
                bfv[nt] = *(const s16x8*)(wb + nt * 1024);

            s16x8 af0, af1;
            if (kk == 0) {
                af0 = s16x8{ (short)f2bf(px0.x), (short)f2bf(px0.y), (short)f2bf(px0.z), (short)f2bf(px0.w),
                             (short)f2bf(px1.x), (short)f2bf(px1.y), (short)f2bf(px1.z), (short)f2bf(px1.w) };
                af1 = s16x8{ (short)f2bf(px4.x), (short)f2bf(px4.y), (short)f2bf(px4.z), (short)f2bf(px4.w),
                             (short)f2bf(px5.x), (short)f2bf(px5.y), (short)f2bf(px5.z), (short)f2bf(px5.w) };
            } else {
                af0 = s16x8{ (short)f2bf(px2.x), (short)f2bf(px2.y), (short)f2bf(px2.z), (short)f2bf(px2.w),
                             (short)f2bf(px3.x), (short)f2bf(px3.y), (short)f2bf(px3.z), (short)f2bf(px3.w) };
                af1 = s16x8{ (short)f2bf(px6.x), (short)f2bf(px6.y), (short)f2bf(px6.z), (short)f2bf(px6.w),
                             (short)f2bf(px7.x), (short)f2bf(px7.y), (short)f2bf(px7.z), (short)f2bf(px7.w) };
            }
#pragma unroll
            for (int nt = 0; nt < 12; nt++) {
                acc[0][nt] = MFMA16(af0, bfv[nt], acc[0][nt], 0, 0, 0);
                acc[1][nt] = MFMA16(af1, bfv[nt], acc[1][nt], 0, 0, 0);
            }
        }
    }
    __syncthreads();   // Wl dead; safe to overwrite Ql/Kl in epilogue

    // ---- epilogue: Q,K row-major; V transposed (acc regs hold 4 consecutive rows) ----
#pragma unroll
    for (int mt = 0; mt < 2; mt++) {
#pragma unroll
        for (int nt = 0; nt < 12; nt++) {
            if (nt < 4) {
#pragma unroll
                for (int r = 0; r < 4; r++)
                    Ql[(m0 + mt * 16 + quad * 4 + r) * 72 + nt * 16 + l15] = f2bf(acc[mt][nt][r]);
            } else if (nt < 8) {
#pragma unroll
                for (int r = 0; r < 4; r++)
                    Kl[(m0 + mt * 16 + quad * 4 + r) * 72 + (nt - 4) * 16 + l15] = f2bf(acc[mt][nt][r]);
            } else {
                ushort4 pv;
                pv.x = f2bf(acc[mt][nt][0]); pv.y = f2bf(acc[mt][nt][1]);
                pv.z = f2bf(acc[mt][nt][2]); pv.w = f2bf(acc[mt][nt][3]);
                *(ushort4*)&Vt[((nt - 8) * 16 + l15) * 264 + m0 + mt * 16 + quad * 4] = pv;
            }
        }
    }
    __syncthreads();

    // ======== phase 2: causal attention ========
    unsigned short* Pw = Pl8 + wid * (16 * 56);

#pragma unroll
    for (int ti = 0; ti < 2; ti++) {
        const int r0 = (ti == 0 ? wid : 15 - wid) * 16;   // balanced tile pair

        s16x8 qf0 = *(const s16x8*)&Ql[(r0 + l15) * 72 + quad * 8];
        s16x8 qf1 = *(const s16x8*)&Ql[(r0 + l15) * 72 + 32 + quad * 8];

        f32x4 o[4] = {};
        float mr[4], lr[4];
#pragma unroll
        for (int r = 0; r < 4; r++) { mr[r] = -1e30f; lr[r] = 0.0f; }

        const int nst = (r0 >> 5) + 1;
        for (int st = 0; st < nst; st++) {
            const int s0 = st * 32;
            s16x8 kf00 = *(const s16x8*)&Kl[(s0 + l15) * 72 + quad * 8];
            s16x8 kf01 = *(const s16x8*)&Kl[(s0 + l15) * 72 + 32 + quad * 8];
            s16x8 kf10 = *(const s16x8*)&Kl[(s0 + 16 + l15) * 72 + quad * 8];
            s16x8 kf11 = *(const s16x8*)&Kl[(s0 + 16 + l15) * 72 + 32 + quad * 8];
            s16x8 vf[4];
#pragma unroll
            for (int n = 0; n < 4; n++)
                vf[n] = *(const s16x8*)&Vt[(n * 16 + l15) * 264 + s0 + quad * 8];

            f32x4 S0 = {0.f, 0.f, 0.f, 0.f}, S1 = {0.f, 0.f, 0.f, 0.f};
            S0 = MFMA16(qf0, kf00, S0, 0, 0, 0);
            S0 = MFMA16(qf1, kf01, S0, 0, 0, 0);
            S1 = MFMA16(qf0, kf10, S1, 0, 0, 0);
            S1 = MFMA16(qf1, kf11, S1, 0, 0, 0);

            if (s0 + 31 > r0) {   // diagonal tile: causal mask
#pragma unroll
                for (int r = 0; r < 4; r++) {
                    int t = r0 + quad * 4 + r;
                    if (s0 + l15 > t)      S0[r] = -1e30f;
                    if (s0 + 16 + l15 > t) S1[r] = -1e30f;
                }
            }

            float a4[4];
#pragma unroll
            for (int r = 0; r < 4; r++) {
                float rm = fmaxf(S0[r], S1[r]);
                rm = fmaxf(rm, __shfl_xor(rm, 1));
                rm = fmaxf(rm, __shfl_xor(rm, 2));
                rm = fmaxf(rm, __shfl_xor(rm, 4));
                rm = fmaxf(rm, __shfl_xor(rm, 8));
                float mn = fmaxf(mr[r], rm);
                float al = exp2f((mr[r] - mn) * 1.44269504f);
                mr[r] = mn;
                float p0 = exp2f((S0[r] - mn) * 1.44269504f);
                float p1 = exp2f((S1[r] - mn) * 1.44269504f);
                float rs = p0 + p1;
                rs += __shfl_xor(rs, 1);
                rs += __shfl_xor(rs, 2);
                rs += __shfl_xor(rs, 4);
                rs += __shfl_xor(rs, 8);
                lr[r] = al * lr[r] + rs;
                a4[r] = al;
                Pw[(quad * 4 + r) * 56 + l15]      = f2bf(p0);
                Pw[(quad * 4 + r) * 56 + l15 + 16] = f2bf(p1);
            }
#pragma unroll
            for (int n = 0; n < 4; n++) {
                f32x4 tt = o[n];
#pragma unroll
                for (int r = 0; r < 4; r++) tt[r] *= a4[r];
                o[n] = tt;
            }
            s16x8 pf = *(const s16x8*)&Pw[l15 * 56 + quad * 8];
#pragma unroll
            for (int n = 0; n < 4; n++)
                o[n] = MFMA16(pf, vf[n], o[n], 0, 0, 0);
        }

        // ---- normalize + store ----
        float inv[4];
#pragma unroll
        for (int r = 0; r < 4; r++) inv[r] = 1.0f / lr[r];
#pragma unroll
        for (int n = 0; n < 4; n++)
#pragma unroll
            for (int r = 0; r < 4; r++) {
                long t = (long)b * 256 + r0 + quad * 4 + r;
                out[t * 64 + n * 16 + l15] = o[n][r] * inv[r];
            }
    }
}

// ---------------------------------------------------------------------------
extern "C" void kernel_launch(void* const* d_in, const int* in_sizes, int n_in,
                              void* d_out, int out_size, void* d_ws, size_t ws_size,
                              hipStream_t stream) {
    const float* x  = (const float*)d_in[0];
    const float* Wk = (const float*)d_in[1];
    const float* Wq = (const float*)d_in[2];
    const float* Wv = (const float*)d_in[3];
    float* out = (float*)d_out;

    unsigned short* wt = (unsigned short*)d_ws;   // 192*1024 bf16

    prep_w<<<192, 256, 0, stream>>>(Wk, Wq, Wv, wt);
    fused_kernel<<<256, 512, 0, stream>>>(x, wt, out);
}